// Round 3
// baseline (2924.721 us; speedup 1.0000x reference)
//
#include <hip/hip_runtime.h>

// DegModel: kernel-prediction net (17x conv3x3 + 1x1 conv to 441 taps) +
// tap-normalized spatially-varying 21x21 downsample (stride 4, reflect pad).
//
// fp64 conv chain (numerics: 1/tap-sum amplification demands taps match the
// np ref to ~1e-9; fp32 chain failed at 1280 vs 1177 threshold, fp64 passes
// at 576). Round 3 = performance restructure, same math:
//  - conv3x3: weights staged in LDS (broadcast ds_read, no sKcache-miss
//    stalls), CCHUNK=8, 4 blocks/CU.
//  - lastconv: GEMM-style register tile (8 taps x 1 pos fp64 acc), h-tile in
//    LDS, weights transposed [c][448] -> one s_load_dwordx16 per c-step.
//    (Round-2 version re-read 512B/thread/tap from L2: 200us at 12% VALU.)

#define NB 8        // batch
#define NF 64       // features
#define SP 4096     // 64*64 spatial
#define K2 441      // 21*21 taps
#define K2P 448     // padded taps (14 chunks x 32)
#define RES_WSTRIDE (64*64*9)

// ---------------------------------------------------------------------------
__global__ void cvt_f32_to_f64(const float* __restrict__ src,
                               double* __restrict__ dst, int n)
{
    int i = blockIdx.x * blockDim.x + threadIdx.x;
    if (i < n) dst[i] = (double)src[i];
}

// transpose last_w (441,64) -> wT (64,448) fp64, zero-pad taps 441..447;
// pad bias to 448.
__global__ void prep_lastw(const float* __restrict__ lw, const float* __restrict__ lb,
                           double* __restrict__ wT, double* __restrict__ bp)
{
    int i = blockIdx.x * blockDim.x + threadIdx.x;
    if (i < 64 * K2P) {
        int c = i / K2P, t = i - c * K2P;
        wT[i] = (t < K2) ? (double)lw[t * 64 + c] : 0.0;
    }
    if (i < K2P) bp[i] = (i < K2) ? (double)lb[i] : 0.0;
}

// ---------------------------------------------------------------------------
// conv3x3 fp64, SAME zero-pad, NCHW. Block: 256 thr = 16x16 spatial tile,
// 16 oc. Grid: 8 b * 16 tiles * 4 oc-groups = 512 blocks.
// Both input chunk AND weight chunk staged in LDS; weight reads are
// wave-uniform broadcasts (conflict-free), input reads 2-way aliased (free).
// LDS 30.7 KB -> 4 blocks/CU with __launch_bounds__(256,4).
// ---------------------------------------------------------------------------
template<int CIN, int CCHUNK, bool RELU, bool RESADD, typename TIN>
__global__ __launch_bounds__(256, 4)
void conv3x3_kernel(const TIN* __restrict__ in, const double* __restrict__ wgt,
                    const double* __restrict__ bias, const double* __restrict__ res,
                    double* __restrict__ out)
{
    const int bid  = blockIdx.x;
    const int ocg  = bid & 3;
    const int tile = (bid >> 2) & 15;
    const int b    = bid >> 6;
    const int i0   = (tile >> 2) << 4;
    const int j0   = (tile & 3) << 4;
    const int tid  = threadIdx.x;
    const int ti   = tid >> 4, tj = tid & 15;
    const int ocBase = ocg * 16;

    __shared__ double s_in[CCHUNK][18][18];   // CCHUNK=8: 20.7 KB
    __shared__ double s_w[CCHUNK][16][12];    // CCHUNK=8: 12.3 KB (pad 9->12: 16B-aligned rows)

    double acc[16];
#pragma unroll
    for (int oc = 0; oc < 16; ++oc) acc[oc] = bias[ocBase + oc];

    for (int cb = 0; cb < CIN; cb += CCHUNK) {
        // stage input chunk (zero pad at image edges)
        for (int e = tid; e < CCHUNK * 324; e += 256) {
            int c   = e / 324;
            int rem = e - c * 324;
            int r   = rem / 18;
            int cc  = rem - r * 18;
            int gr  = i0 + r - 1;
            int gc  = j0 + cc - 1;
            double v = 0.0;
            if (gr >= 0 && gr < 64 && gc >= 0 && gc < 64)
                v = (double)in[((b * CIN + cb + c) * 64 + gr) * 64 + gc];
            s_in[c][r][cc] = v;
        }
        // stage weight chunk: 16 oc x CCHUNK c x 9
        for (int e = tid; e < CCHUNK * 144; e += 256) {
            int c   = e / 144;
            int rem = e - c * 144;
            int oc  = rem / 9;
            int k   = rem - oc * 9;
            s_w[c][oc][k] = wgt[((ocBase + oc) * CIN + cb + c) * 9 + k];
        }
        __syncthreads();

        for (int c = 0; c < CCHUNK; ++c) {
            double v[9];
#pragma unroll
            for (int dy = 0; dy < 3; ++dy)
#pragma unroll
                for (int dx = 0; dx < 3; ++dx)
                    v[dy * 3 + dx] = s_in[c][ti + dy][tj + dx];
#pragma unroll
            for (int oc = 0; oc < 16; ++oc) {
                double a = acc[oc];
#pragma unroll
                for (int k = 0; k < 9; ++k) a = fma(s_w[c][oc][k], v[k], a);
                acc[oc] = a;
            }
        }
        __syncthreads();
    }

    const int pi = i0 + ti, pj = j0 + tj;
#pragma unroll
    for (int oc = 0; oc < 16; ++oc) {
        int idx = ((b * NF + ocBase + oc) * 64 + pi) * 64 + pj;
        double val = acc[oc];
        if (RELU)   val = fmax(val, 0.0);
        if (RESADD) val += res[idx];
        out[idx] = val;
    }
}

// ---------------------------------------------------------------------------
// 1x1 conv h(64ch fp64) -> 448 (441+pad) taps. Block = (b, 64-pos tile);
// h-tile (64c x 64pos, 32 KB) in LDS; wave w handles taps it*32+w*8..+8
// for it in [0,14). Weights transposed [c][448]: per c-step one wave-uniform
// s_load_dwordx16 + one ds_read_b64 + 8 v_fma_f64. Raw taps stored fp32 to
// d_out kernel region; per-pos fp64 tap-sum via deterministic LDS reduce.
// Grid: 8 b * 64 tiles = 512 blocks.
// ---------------------------------------------------------------------------
__global__ __launch_bounds__(256, 2)
void lastconv_kernel(const double* __restrict__ h, const double* __restrict__ wT,
                     const double* __restrict__ biasp, float* __restrict__ kraw,
                     double* __restrict__ sums)
{
    const int b    = blockIdx.x >> 6;
    const int p0   = (blockIdx.x & 63) << 6;
    const int tid  = threadIdx.x;
    const int lane = tid & 63;

    __shared__ double s_h[64][64];     // [c][pos] 32 KB; lane-consecutive b64 = free
    __shared__ double s_red[4][64];

    for (int e = tid; e < 4096; e += 256) {
        int c = e >> 6, p = e & 63;
        s_h[c][p] = h[(b * NF + c) * SP + p0 + p];
    }
    __syncthreads();

    const int wv = __builtin_amdgcn_readfirstlane(tid >> 6);  // uniform wave id
    double ssum = 0.0;

    for (int it = 0; it < 14; ++it) {
        const int t0 = it * 32 + wv * 8;
        double acc[8];
#pragma unroll
        for (int j = 0; j < 8; ++j) acc[j] = biasp[t0 + j];
#pragma unroll
        for (int c = 0; c < 64; ++c) {
            double hd = s_h[c][lane];
            const double* wp = wT + c * K2P + t0;   // uniform -> s_load_dwordx16
#pragma unroll
            for (int j = 0; j < 8; ++j) acc[j] = fma(wp[j], hd, acc[j]);
        }
#pragma unroll
        for (int j = 0; j < 8; ++j) {
            int t = t0 + j;
            if (t < K2) kraw[(b * K2 + t) * SP + p0 + lane] = (float)acc[j];
            ssum += acc[j];   // pad taps are exactly 0 (zero weights+bias)
        }
    }

    s_red[tid >> 6][lane] = ssum;
    __syncthreads();
    if (tid < 64)
        sums[b * SP + p0 + tid] =
            (s_red[0][tid] + s_red[1][tid]) + (s_red[2][tid] + s_red[3][tid]);
}

// ---------------------------------------------------------------------------
// Normalize kernel in place + apply to reflect-padded 21x21 patches of x.
// (unchanged from round 2 except single sums array) — numerics here are not
// 1/s-amplified, fp32 ok.
// ---------------------------------------------------------------------------
__global__ __launch_bounds__(256)
void apply_kernel(const float* __restrict__ x, const double* __restrict__ sums,
                  float* __restrict__ kout, float* __restrict__ out)
{
    const int bid  = blockIdx.x;
    const int g    = bid & 3;
    const int tile = (bid >> 2) & 15;
    const int b    = bid >> 6;
    const int i0   = (tile >> 2) << 4;
    const int j0   = (tile & 3) << 4;
    const int tid  = threadIdx.x;
    const int ti   = tid >> 4, tj = tid & 15;

    __shared__ float s_x[3][81][84];   // 81,648 B

    for (int e = tid; e < 3 * 81 * 84; e += 256) {
        int c   = e / 6804;
        int rem = e - c * 6804;
        int u   = rem / 84;
        int v   = rem - u * 84;
        int gr  = i0 * 4 + u - 10;
        int gc  = j0 * 4 + v - 10;
        gr = gr < 0 ? -gr : (gr > 255 ? 510 - gr : gr);
        gc = gc < 0 ? -gc : (gc > 255 ? 510 - gc : gc);
        int vp = (v & 3) * 21 + (v >> 2);
        s_x[c][u][vp] = x[((b * 3 + c) * 256 + gr) * 256 + gc];
    }
    __syncthreads();

    const int p = (i0 + ti) * 64 + (j0 + tj);
    const double inv = 1.0 / (sums[b * SP + p] + 1e-8);

    float o0 = 0.f, o1 = 0.f, o2 = 0.f;
    const int t0 = g * 111;
    const int t1 = (t0 + 111 < K2) ? t0 + 111 : K2;
    for (int t = t0; t < t1; ++t) {
        int ty = t / 21, tx = t - ty * 21;
        float* kp = &kout[(b * K2 + t) * SP + p];
        float k  = *kp;
        float kn = (float)((double)k * inv);
        *kp = kn;
        int u  = ti * 4 + ty;
        int vp = (tx & 3) * 21 + tj + (tx >> 2);
        o0 = fmaf(s_x[0][u][vp], kn, o0);
        o1 = fmaf(s_x[1][u][vp], kn, o1);
        o2 = fmaf(s_x[2][u][vp], kn, o2);
    }
    atomicAdd(&out[(b * 3 + 0) * SP + p], o0);
    atomicAdd(&out[(b * 3 + 1) * SP + p], o1);
    atomicAdd(&out[(b * 3 + 2) * SP + p], o2);
}

// ---------------------------------------------------------------------------
extern "C" void kernel_launch(void* const* d_in, const int* in_sizes, int n_in,
                              void* d_out, int out_size, void* d_ws, size_t ws_size,
                              hipStream_t stream)
{
    (void)in_sizes; (void)n_in; (void)out_size; (void)ws_size;

    const float* x = (const float*)d_in[0];
    const float* z = (const float*)d_in[1];

    float* out  = (float*)d_out;                 // (8,3,64,64)
    float* kout = (float*)d_out + NB * 3 * SP;   // (8,441,64,64) raw -> normalized

    // ws layout (doubles): converted weights | h | t (sums alias t)
    double* wd = (double*)d_ws;
    const int n_c0w = NF * 3 * 9;          // 1728
    const int n_c0b = NF;                  // 64
    const int n_rw  = 8 * NF * NF * 9;     // 294912
    const int n_rb  = 8 * NF;              // 512
    const int n_lwT = 64 * K2P;            // 28672
    const int n_lb  = K2P;                 // 448

    double* c0w = wd;
    double* c0b = c0w + n_c0w;
    double* rw1 = c0b + n_c0b;
    double* rb1 = rw1 + n_rw;
    double* rw2 = rb1 + n_rb;
    double* rb2 = rw2 + n_rw;
    double* lwT = rb2 + n_rb;
    double* lbp = lwT + n_lwT;
    double* h   = lbp + n_lb;              // ~5.0 MB of weights before this
    double* t   = h + NB * NF * SP;        // 16.8 MB each
    double* sums = t;                      // aliases t (free after conv chain)

    // convert conv weights/biases to fp64 in ws
    {
        const float* srcs[6] = {(const float*)d_in[2], (const float*)d_in[3],
                                (const float*)d_in[4], (const float*)d_in[5],
                                (const float*)d_in[6], (const float*)d_in[7]};
        double* dsts[6] = {c0w, c0b, rw1, rb1, rw2, rb2};
        const int ns[6] = {n_c0w, n_c0b, n_rw, n_rb, n_rw, n_rb};
        for (int i = 0; i < 6; ++i)
            cvt_f32_to_f64<<<(ns[i] + 255) / 256, 256, 0, stream>>>(srcs[i], dsts[i], ns[i]);
    }
    prep_lastw<<<(64 * K2P + 255) / 256, 256, 0, stream>>>(
        (const float*)d_in[8], (const float*)d_in[9], lwT, lbp);

    hipMemsetAsync(out, 0, NB * 3 * SP * sizeof(float), stream);

    conv3x3_kernel<3, 3, false, false, float><<<512, 256, 0, stream>>>(z, c0w, c0b, nullptr, h);
    for (int i = 0; i < 8; ++i) {
        conv3x3_kernel<64, 8, true,  false, double><<<512, 256, 0, stream>>>(
            h, rw1 + i * RES_WSTRIDE, rb1 + i * 64, nullptr, t);
        conv3x3_kernel<64, 8, false, true,  double><<<512, 256, 0, stream>>>(
            t, rw2 + i * RES_WSTRIDE, rb2 + i * 64, h, h);
    }
    lastconv_kernel<<<512, 256, 0, stream>>>(h, lwT, lbp, kout, sums);
    apply_kernel<<<512, 256, 0, stream>>>(x, sums, kout, out);
}

// Round 4
// 2043.386 us; speedup vs baseline: 1.4313x; 1.4313x over previous
//
#include <hip/hip_runtime.h>

// DegModel: kernel-prediction net (17x conv3x3 + 1x1 conv to 441 taps) +
// tap-normalized spatially-varying 21x21 downsample (stride 4, reflect pad).
//
// fp64 conv chain (1/tap-sum amplification: fp32 chain fails 1280 > 1177;
// fp64 passes at 576). Round 4 = keep math, fix operand pipes:
//  - conv3x3: weights PRE-TRANSPOSED to [ocg][c][16oc*9] contiguous fp64 and
//    fetched via wave-uniform scalar loads (9.2 KB/chunk <= 16 KB sK$; ocg
//    slowest in grid so co-resident blocks share the slice). LDS holds only
//    the input tile: 9 ds_read_b64 per 144 FMA. (Round 3 re-read every
//    weight from LDS per FMA: 155 GB LDS traffic = the whole 2.2 ms chain.)
//  - lastconv: fp64 GEMM with BOTH operands in LDS, register tile 8 taps x
//    2 pos; 64-tap weight chunks staged per iteration. (Round 3's scalar-
//    load version serialized on 64 unpipelineable s_load_dwordx16/chunk.)

#define NB 8        // batch
#define NF 64       // features
#define SP 4096     // 64*64 spatial
#define K2 441      // 21*21 taps
#define K2P 448     // padded taps (7 chunks x 64)
#define RES_WSTRIDE (64*64*9)
#define RES_TSTRIDE (64*576)   // transformed per-layer stride (doubles)

// ---------------------------------------------------------------------------
__global__ void cvt_f32_to_f64(const float* __restrict__ src,
                               double* __restrict__ dst, int n)
{
    int i = blockIdx.x * blockDim.x + threadIdx.x;
    if (i < n) dst[i] = (double)src[i];
}

// conv weights OIHW fp32 -> [layer][ocg][c][oc16][k9] fp64 (contiguous 144
// doubles per (ocg,c) = one c-step's scalar-load row).
__global__ void prep_convw(const float* __restrict__ src, double* __restrict__ dst,
                           int CIN, int nlayer, int wstride)
{
    int i = blockIdx.x * blockDim.x + threadIdx.x;
    int M = CIN * 576;                  // per-layer transformed count
    if (i >= nlayer * M) return;
    int l   = i / M;
    int r   = i - l * M;
    int ocg = r / (CIN * 144);
    int r2  = r - ocg * (CIN * 144);
    int c   = r2 / 144;
    int q   = r2 - c * 144;
    int oc  = q / 9;
    int k   = q - oc * 9;
    dst[i] = (double)src[l * wstride + ((ocg * 16 + oc) * CIN + c) * 9 + k];
}

// last_w (441,64) -> wT (64,448) fp64, zero-pad taps 441..447; pad bias.
__global__ void prep_lastw(const float* __restrict__ lw, const float* __restrict__ lb,
                           double* __restrict__ wT, double* __restrict__ bp)
{
    int i = blockIdx.x * blockDim.x + threadIdx.x;
    if (i < 64 * K2P) {
        int c = i / K2P, t = i - c * K2P;
        wT[i] = (t < K2) ? (double)lw[t * 64 + c] : 0.0;
    }
    if (i < K2P) bp[i] = (i < K2) ? (double)lb[i] : 0.0;
}

// ---------------------------------------------------------------------------
// conv3x3 fp64, SAME zero-pad, NCHW. Block: 256 thr = 16x16 spatial tile,
// 16 oc/thread. Grid 512: bid = ocg*128 + b*16 + tile (ocg SLOWEST so the
// ~2 co-resident blocks/CU share the same 9.2 KB weight chunk in sK$).
// Weights via wave-uniform scalar loads from the transformed layout; LDS
// holds only the input tile (CCHUNK=8: 20.7 KB -> 2 blocks/CU fit easily).
// ---------------------------------------------------------------------------
template<int CIN, int CCHUNK, bool RELU, bool RESADD, typename TIN>
__global__ __launch_bounds__(256, 2)
void conv3x3_kernel(const TIN* __restrict__ in, const double* __restrict__ wgtT,
                    const double* __restrict__ bias, const double* __restrict__ res,
                    double* __restrict__ out)
{
    const int bid  = blockIdx.x;
    const int ocg  = bid >> 7;          // slowest
    const int b    = (bid >> 4) & 7;
    const int tile = bid & 15;
    const int i0   = (tile >> 2) << 4;
    const int j0   = (tile & 3) << 4;
    const int tid  = threadIdx.x;
    const int ti   = tid >> 4, tj = tid & 15;
    const int ocBase = ocg * 16;

    __shared__ double s_in[CCHUNK][18][18];   // CCHUNK=8: 20.7 KB

    const double* wbase = wgtT + ocg * CIN * 144;

    double acc[16];
#pragma unroll
    for (int oc = 0; oc < 16; ++oc) acc[oc] = bias[ocBase + oc];

    for (int cb = 0; cb < CIN; cb += CCHUNK) {
        // stage input chunk (zero pad at image edges)
        for (int e = tid; e < CCHUNK * 324; e += 256) {
            int c   = e / 324;
            int rem = e - c * 324;
            int r   = rem / 18;
            int cc  = rem - r * 18;
            int gr  = i0 + r - 1;
            int gc  = j0 + cc - 1;
            double v = 0.0;
            if (gr >= 0 && gr < 64 && gc >= 0 && gc < 64)
                v = (double)in[((b * CIN + cb + c) * 64 + gr) * 64 + gc];
            s_in[c][r][cc] = v;
        }
        __syncthreads();

        for (int c = 0; c < CCHUNK; ++c) {
            const double* wrow = wbase + (cb + c) * 144;   // uniform, contiguous
            double v[9];
#pragma unroll
            for (int dy = 0; dy < 3; ++dy)
#pragma unroll
                for (int dx = 0; dx < 3; ++dx)
                    v[dy * 3 + dx] = s_in[c][ti + dy][tj + dx];
#pragma unroll
            for (int oc = 0; oc < 16; ++oc) {
                double a = acc[oc];
#pragma unroll
                for (int k = 0; k < 9; ++k) a = fma(wrow[oc * 9 + k], v[k], a);
                acc[oc] = a;
            }
        }
        __syncthreads();
    }

    const int pi = i0 + ti, pj = j0 + tj;
#pragma unroll
    for (int oc = 0; oc < 16; ++oc) {
        int idx = ((b * NF + ocBase + oc) * 64 + pi) * 64 + pj;
        double val = acc[oc];
        if (RELU)   val = fmax(val, 0.0);
        if (RESADD) val += res[idx];
        out[idx] = val;
    }
}

// ---------------------------------------------------------------------------
// 1x1 conv h(64ch fp64) -> 448 (441+pad) taps. Block = (b, 64-pos tile),
// 256 thr: octet o = tid>>5 (8 taps), pos-pair pp = tid&31 (2 consecutive
// pos). h-tile (32 KB) staged once; 64-tap weight chunk (32 KB) staged per
// iteration. Inner c-step: 4 half-wave-broadcast w reads + 1 b128 h read per
// 16 FMA. Raw taps stored fp32 (float2) into d_out kernel region; per-pos
// fp64 tap-sum via deterministic LDS reduce over the 8 octets.
// Grid: 8 b * 64 tiles = 512 blocks.
// ---------------------------------------------------------------------------
__global__ __launch_bounds__(256, 2)
void lastconv_kernel(const double* __restrict__ h, const double* __restrict__ wT,
                     const double* __restrict__ biasp, float* __restrict__ kraw,
                     double* __restrict__ sums)
{
    const int b   = blockIdx.x >> 6;
    const int p0  = (blockIdx.x & 63) << 6;
    const int tid = threadIdx.x;
    const int o   = tid >> 5;        // tap octet 0..7
    const int pp  = tid & 31;        // pos pair 0..31
    const int p   = pp * 2;
    const int o8  = o * 8;

    __shared__ double s_h[64][64];   // [c][pos]  32 KB
    __shared__ double s_w[64][64];   // [c][tap]  32 KB (per 64-tap chunk)
    __shared__ double s_red[8][64];  // 4 KB

    for (int e = tid; e < 4096; e += 256) {
        int c = e >> 6, q = e & 63;
        s_h[c][q] = h[(b * NF + c) * SP + p0 + q];
    }

    double sp0 = 0.0, sp1 = 0.0;

    for (int it = 0; it < 7; ++it) {
        __syncthreads();             // prev chunk compute done (covers s_h it=0)
        for (int e = tid; e < 4096; e += 256) {
            int c = e >> 6, t = e & 63;
            s_w[c][t] = wT[c * K2P + it * 64 + t];
        }
        __syncthreads();

        const int t0 = it * 64 + o8;
        double acc[8][2];
#pragma unroll
        for (int j = 0; j < 8; ++j) { acc[j][0] = biasp[t0 + j]; acc[j][1] = acc[j][0]; }

#pragma unroll 16
        for (int c = 0; c < 64; ++c) {
            double h0 = s_h[c][p];
            double h1 = s_h[c][p + 1];
#pragma unroll
            for (int j = 0; j < 8; ++j) {
                double w = s_w[c][o8 + j];
                acc[j][0] = fma(w, h0, acc[j][0]);
                acc[j][1] = fma(w, h1, acc[j][1]);
            }
        }

#pragma unroll
        for (int j = 0; j < 8; ++j) {
            int T = t0 + j;
            sp0 += acc[j][0];        // pad taps are exactly 0 (zero w+bias)
            sp1 += acc[j][1];
            if (T < K2) {
                float2 v = make_float2((float)acc[j][0], (float)acc[j][1]);
                *(float2*)&kraw[(b * K2 + T) * SP + p0 + p] = v;
            }
        }
    }

    s_red[o][p]     = sp0;
    s_red[o][p + 1] = sp1;
    __syncthreads();
    if (tid < 64) {
        double s = 0.0;
#pragma unroll
        for (int oo = 0; oo < 8; ++oo) s += s_red[oo][tid];
        sums[b * SP + p0 + tid] = s;
    }
}

// ---------------------------------------------------------------------------
// Normalize kernel in place + apply to reflect-padded 21x21 patches of x.
// (unchanged — numerics here are not 1/s-amplified, fp32 ok)
// ---------------------------------------------------------------------------
__global__ __launch_bounds__(256)
void apply_kernel(const float* __restrict__ x, const double* __restrict__ sums,
                  float* __restrict__ kout, float* __restrict__ out)
{
    const int bid  = blockIdx.x;
    const int g    = bid & 3;
    const int tile = (bid >> 2) & 15;
    const int b    = bid >> 6;
    const int i0   = (tile >> 2) << 4;
    const int j0   = (tile & 3) << 4;
    const int tid  = threadIdx.x;
    const int ti   = tid >> 4, tj = tid & 15;

    __shared__ float s_x[3][81][84];   // 81,648 B

    for (int e = tid; e < 3 * 81 * 84; e += 256) {
        int c   = e / 6804;
        int rem = e - c * 6804;
        int u   = rem / 84;
        int v   = rem - u * 84;
        int gr  = i0 * 4 + u - 10;
        int gc  = j0 * 4 + v - 10;
        gr = gr < 0 ? -gr : (gr > 255 ? 510 - gr : gr);
        gc = gc < 0 ? -gc : (gc > 255 ? 510 - gc : gc);
        int vp = (v & 3) * 21 + (v >> 2);
        s_x[c][u][vp] = x[((b * 3 + c) * 256 + gr) * 256 + gc];
    }
    __syncthreads();

    const int p = (i0 + ti) * 64 + (j0 + tj);
    const double inv = 1.0 / (sums[b * SP + p] + 1e-8);

    float o0 = 0.f, o1 = 0.f, o2 = 0.f;
    const int t0 = g * 111;
    const int t1 = (t0 + 111 < K2) ? t0 + 111 : K2;
    for (int t = t0; t < t1; ++t) {
        int ty = t / 21, tx = t - ty * 21;
        float* kp = &kout[(b * K2 + t) * SP + p];
        float k  = *kp;
        float kn = (float)((double)k * inv);
        *kp = kn;
        int u  = ti * 4 + ty;
        int vp = (tx & 3) * 21 + tj + (tx >> 2);
        o0 = fmaf(s_x[0][u][vp], kn, o0);
        o1 = fmaf(s_x[1][u][vp], kn, o1);
        o2 = fmaf(s_x[2][u][vp], kn, o2);
    }
    atomicAdd(&out[(b * 3 + 0) * SP + p], o0);
    atomicAdd(&out[(b * 3 + 1) * SP + p], o1);
    atomicAdd(&out[(b * 3 + 2) * SP + p], o2);
}

// ---------------------------------------------------------------------------
extern "C" void kernel_launch(void* const* d_in, const int* in_sizes, int n_in,
                              void* d_out, int out_size, void* d_ws, size_t ws_size,
                              hipStream_t stream)
{
    (void)in_sizes; (void)n_in; (void)out_size; (void)ws_size;

    const float* x = (const float*)d_in[0];
    const float* z = (const float*)d_in[1];

    float* out  = (float*)d_out;                 // (8,3,64,64)
    float* kout = (float*)d_out + NB * 3 * SP;   // (8,441,64,64) raw -> normalized

    // ws layout (doubles)
    double* wd = (double*)d_ws;
    const int n_c0wT = 3 * 576;            // 1728
    const int n_rwT  = 8 * RES_TSTRIDE;    // 294912 each
    double* c0wT = wd;
    double* rwT1 = c0wT + n_c0wT;
    double* rwT2 = rwT1 + n_rwT;
    double* c0b  = rwT2 + n_rwT;
    double* rb1  = c0b + 64;
    double* rb2  = rb1 + 512;
    double* lwT  = rb2 + 512;              // 64*448
    double* lbp  = lwT + 64 * K2P;         // 448
    double* h    = lbp + K2P;
    double* t    = h + NB * NF * SP;       // 16.8 MB each
    double* sums = t;                      // aliases t (free after conv chain)

    // weight prep
    prep_convw<<<(3 * 576 + 255) / 256, 256, 0, stream>>>(
        (const float*)d_in[2], c0wT, 3, 1, 0);
    prep_convw<<<(8 * 64 * 576 + 255) / 256, 256, 0, stream>>>(
        (const float*)d_in[4], rwT1, 64, 8, RES_WSTRIDE);
    prep_convw<<<(8 * 64 * 576 + 255) / 256, 256, 0, stream>>>(
        (const float*)d_in[6], rwT2, 64, 8, RES_WSTRIDE);
    cvt_f32_to_f64<<<1, 64,  0, stream>>>((const float*)d_in[3], c0b, 64);
    cvt_f32_to_f64<<<2, 256, 0, stream>>>((const float*)d_in[5], rb1, 512);
    cvt_f32_to_f64<<<2, 256, 0, stream>>>((const float*)d_in[7], rb2, 512);
    prep_lastw<<<(64 * K2P + 255) / 256, 256, 0, stream>>>(
        (const float*)d_in[8], (const float*)d_in[9], lwT, lbp);

    hipMemsetAsync(out, 0, NB * 3 * SP * sizeof(float), stream);

    conv3x3_kernel<3, 3, false, false, float><<<512, 256, 0, stream>>>(z, c0wT, c0b, nullptr, h);
    for (int i = 0; i < 8; ++i) {
        conv3x3_kernel<64, 8, true,  false, double><<<512, 256, 0, stream>>>(
            h, rwT1 + i * RES_TSTRIDE, rb1 + i * 64, nullptr, t);
        conv3x3_kernel<64, 8, false, true,  double><<<512, 256, 0, stream>>>(
            t, rwT2 + i * RES_TSTRIDE, rb2 + i * 64, h, h);
    }
    lastconv_kernel<<<512, 256, 0, stream>>>(h, lwT, lbp, kout, sums);
    apply_kernel<<<512, 256, 0, stream>>>(x, sums, kout, out);
}

// Round 5
// 1933.601 us; speedup vs baseline: 1.5126x; 1.0568x over previous
//
#include <hip/hip_runtime.h>

// DegModel: kernel-prediction net (17x conv3x3 + 1x1 conv to 441 taps) +
// tap-normalized spatially-varying 21x21 downsample (stride 4, reflect pad).
//
// fp64 conv chain (1/tap-sum amplification: fp32 chain fails 1280 > 1177;
// fp64 passes at 576). Round 5 = latency hiding for the conv chain:
//  - grid 1024 (8 oc/thread, 8 ocg) -> 4 blocks/CU (round 4: grid 512 = 2/CU,
//    VALUBusy 32%, 124 us/layer vs 30.7 us fp64-FMA floor).
//  - activations stored zero-padded (66x66): staging is branch-free and
//    async (__builtin_amdgcn_global_load_lds, 16B) into a double-buffered
//    LDS tile; one barrier per c-chunk drains an already-complete prefetch.
//  - weights stay on the scalar pipe (round-4 layout, [ocg][c][8oc*9]).
//  - ds_read costs ~6 cyc/instr regardless of broadcast (m134) -> weights
//    must NOT come from LDS (round-3 lesson).

#define NB 8        // batch
#define NF 64       // features
#define SP 4096     // 64*64 spatial
#define PS 66       // padded spatial dim
#define PS2 4356    // 66*66
#define K2 441      // 21*21 taps
#define K2P 448     // padded taps (7 chunks x 64)
#define RES_WSTRIDE (64*64*9)
#define RES_TSTRIDE (64*576)   // transformed per-layer stride (doubles)

// ---------------------------------------------------------------------------
__global__ void cvt_f32_to_f64(const float* __restrict__ src,
                               double* __restrict__ dst, int n)
{
    int i = blockIdx.x * blockDim.x + threadIdx.x;
    if (i < n) dst[i] = (double)src[i];
}

// z (8,3,64,64) fp32 -> zp (8,3,66,66) fp64 interior (borders pre-zeroed)
__global__ void prep_zpad(const float* __restrict__ z, double* __restrict__ zp)
{
    int i = blockIdx.x * blockDim.x + threadIdx.x;
    if (i >= NB * 3 * SP) return;
    int bc = i >> 12, p = i & 4095, y = p >> 6, x = p & 63;
    zp[(size_t)(bc * PS + y + 1) * PS + x + 1] = (double)z[i];
}

// conv weights OIHW fp32 -> [layer][ocg8][c][oc8][k9] fp64 (contiguous 72
// doubles per (ocg,c) = one c-step's scalar-load row).
__global__ void prep_convw(const float* __restrict__ src, double* __restrict__ dst,
                           int CIN, int nlayer, int wstride)
{
    int i = blockIdx.x * blockDim.x + threadIdx.x;
    int M = CIN * 576;                  // per-layer transformed count
    if (i >= nlayer * M) return;
    int l   = i / M;
    int r   = i - l * M;
    int ocg = r / (CIN * 72);
    int r2  = r - ocg * (CIN * 72);
    int c   = r2 / 72;
    int q   = r2 - c * 72;
    int oc  = q / 9;
    int k   = q - oc * 9;
    dst[i] = (double)src[l * wstride + ((ocg * 8 + oc) * CIN + c) * 9 + k];
}

// last_w (441,64) -> wT (64,448) fp64, zero-pad taps 441..447; pad bias.
__global__ void prep_lastw(const float* __restrict__ lw, const float* __restrict__ lb,
                           double* __restrict__ wT, double* __restrict__ bp)
{
    int i = blockIdx.x * blockDim.x + threadIdx.x;
    if (i < 64 * K2P) {
        int c = i / K2P, t = i - c * K2P;
        wT[i] = (t < K2) ? (double)lw[t * 64 + c] : 0.0;
    }
    if (i < K2P) bp[i] = (i < K2) ? (double)lb[i] : 0.0;
}

// ---------------------------------------------------------------------------
// conv3x3 fp64 on zero-padded NCHW (66x66). Block: 256 thr = 16x16 spatial
// tile, 8 oc/thread. Grid 1024: bid = tile*64 + b*8 + ocg (ocg fastest so
// co-resident blocks bid+256k share ocg -> weight L2/sK$ locality; adjacent
// bids share the input tile -> input L2 locality). 4 blocks/CU.
// Input chunks staged async (global_load_lds 16B) into double-buffered LDS;
// weights via wave-uniform scalar loads from the transformed layout.
// ---------------------------------------------------------------------------
template<int CIN, int CCHUNK, bool RELU, bool RESADD>
__global__ __launch_bounds__(256, 4)
void conv3x3_kernel(const double* __restrict__ in, const double* __restrict__ wgtT,
                    const double* __restrict__ bias, const double* __restrict__ res,
                    double* __restrict__ out)
{
    constexpr int NPAIR = CCHUNK * 162;          // 16B pairs per chunk (18r x 9pr x c)
    constexpr int NSTG  = (NPAIR + 255) / 256;   // full-wave staging iterations
    constexpr int PADP  = NSTG * 256;            // padded pair count (LDS slack)

    const int bid  = blockIdx.x;
    const int ocg  = bid & 7;                    // fastest
    const int b    = (bid >> 3) & 7;
    const int tile = bid >> 6;                   // 0..15
    const int i0   = (tile >> 2) << 4;
    const int j0   = (tile & 3) << 4;
    const int tid  = threadIdx.x;
    const int ti   = tid >> 4, tj = tid & 15;

    __shared__ double s_in[2][PADP * 2];

    const double* wbase = wgtT + (size_t)ocg * CIN * 72;
    const double* gb    = in + (size_t)b * CIN * PS2;

    double acc[8];
#pragma unroll
    for (int oc = 0; oc < 8; ++oc) acc[oc] = bias[ocg * 8 + oc];

    auto stage = [&](int cb, int bf) {
#pragma unroll
        for (int k = 0; k < NSTG; ++k) {
            int e  = tid + k * 256;
            int e2 = (e < NPAIR) ? e : 0;        // clamp: slack lanes reload pair 0
            int c  = e2 / 162;
            int rm = e2 - c * 162;
            int r  = rm / 9;
            int pr = rm - r * 9;
            const double* gp = gb + (size_t)(cb + c) * PS2 + (i0 + r) * PS + j0 + 2 * pr;
            __builtin_amdgcn_global_load_lds(
                (const __attribute__((address_space(1))) void*)gp,
                (__attribute__((address_space(3))) void*)&s_in[bf][e * 2],
                16, 0, 0);
        }
    };

    stage(0, 0);
    __syncthreads();                             // drains vmcnt before barrier

    int bf = 0;
    for (int cb = 0; cb < CIN; cb += CCHUNK) {
        if (cb + CCHUNK < CIN) stage(cb + CCHUNK, bf ^ 1);   // async prefetch
#pragma unroll
        for (int c = 0; c < CCHUNK; ++c) {
            const double* wrow = wbase + (size_t)(cb + c) * 72;  // uniform -> s_load
            const double* sc   = &s_in[bf][c * 324];
            double v[9];
#pragma unroll
            for (int dy = 0; dy < 3; ++dy)
#pragma unroll
                for (int dx = 0; dx < 3; ++dx)
                    v[dy * 3 + dx] = sc[(ti + dy) * 18 + tj + dx];
#pragma unroll
            for (int oc = 0; oc < 8; ++oc) {
                double a = acc[oc];
#pragma unroll
                for (int k = 0; k < 9; ++k) a = fma(wrow[oc * 9 + k], v[k], a);
                acc[oc] = a;
            }
        }
        __syncthreads();                         // prefetch landed + reads done
        bf ^= 1;
    }

    const int pi = i0 + ti + 1, pj = j0 + tj + 1;
#pragma unroll
    for (int oc = 0; oc < 8; ++oc) {
        size_t idx = ((size_t)(b * NF + ocg * 8 + oc) * PS + pi) * PS + pj;
        double val = acc[oc];
        if (RELU)   val = fmax(val, 0.0);
        if (RESADD) val += res[idx];
        out[idx] = val;
    }
}

// ---------------------------------------------------------------------------
// 1x1 conv h(64ch fp64, padded layout) -> 448 (441+pad) taps. Block = (b,
// 64-pos row), 256 thr: octet o = tid>>5 (8 taps), pos-pair pp = tid&31.
// h-row-tile (32 KB) staged once; 64-tap weight chunk (32 KB) per iteration.
// Raw taps stored fp32 (float2) into d_out kernel region; per-pos fp64
// tap-sum via deterministic LDS reduce. Grid: 8 b * 64 rows = 512 blocks.
// ---------------------------------------------------------------------------
__global__ __launch_bounds__(256, 2)
void lastconv_kernel(const double* __restrict__ hp, const double* __restrict__ wT,
                     const double* __restrict__ biasp, float* __restrict__ kraw,
                     double* __restrict__ sums)
{
    const int b   = blockIdx.x >> 6;
    const int row = blockIdx.x & 63;
    const int p0  = row << 6;
    const int tid = threadIdx.x;
    const int o   = tid >> 5;        // tap octet 0..7
    const int pp  = tid & 31;        // pos pair 0..31
    const int p   = pp * 2;
    const int o8  = o * 8;

    __shared__ double s_h[64][64];   // [c][pos]  32 KB
    __shared__ double s_w[64][64];   // [c][tap]  32 KB (per 64-tap chunk)
    __shared__ double s_red[8][64];  // 4 KB

    for (int e = tid; e < 4096; e += 256) {
        int c = e >> 6, q = e & 63;
        s_h[c][q] = hp[(size_t)(b * NF + c) * PS2 + (row + 1) * PS + 1 + q];
    }

    double sp0 = 0.0, sp1 = 0.0;

    for (int it = 0; it < 7; ++it) {
        __syncthreads();             // prev chunk compute done (covers s_h it=0)
        for (int e = tid; e < 4096; e += 256) {
            int c = e >> 6, t = e & 63;
            s_w[c][t] = wT[c * K2P + it * 64 + t];
        }
        __syncthreads();

        const int t0 = it * 64 + o8;
        double acc[8][2];
#pragma unroll
        for (int j = 0; j < 8; ++j) { acc[j][0] = biasp[t0 + j]; acc[j][1] = acc[j][0]; }

#pragma unroll 16
        for (int c = 0; c < 64; ++c) {
            double h0 = s_h[c][p];
            double h1 = s_h[c][p + 1];
#pragma unroll
            for (int j = 0; j < 8; ++j) {
                double w = s_w[c][o8 + j];
                acc[j][0] = fma(w, h0, acc[j][0]);
                acc[j][1] = fma(w, h1, acc[j][1]);
            }
        }

#pragma unroll
        for (int j = 0; j < 8; ++j) {
            int T = t0 + j;
            sp0 += acc[j][0];        // pad taps are exactly 0 (zero w+bias)
            sp1 += acc[j][1];
            if (T < K2) {
                float2 v = make_float2((float)acc[j][0], (float)acc[j][1]);
                *(float2*)&kraw[(size_t)(b * K2 + T) * SP + p0 + p] = v;
            }
        }
    }

    s_red[o][p]     = sp0;
    s_red[o][p + 1] = sp1;
    __syncthreads();
    if (tid < 64) {
        double s = 0.0;
#pragma unroll
        for (int oo = 0; oo < 8; ++oo) s += s_red[oo][tid];
        sums[b * SP + p0 + tid] = s;
    }
}

// ---------------------------------------------------------------------------
// Normalize kernel in place + apply to reflect-padded 21x21 patches of x.
// (numerics here are not 1/s-amplified, fp32 ok)
// ---------------------------------------------------------------------------
__global__ __launch_bounds__(256)
void apply_kernel(const float* __restrict__ x, const double* __restrict__ sums,
                  float* __restrict__ kout, float* __restrict__ out)
{
    const int bid  = blockIdx.x;
    const int g    = bid & 3;
    const int tile = (bid >> 2) & 15;
    const int b    = bid >> 6;
    const int i0   = (tile >> 2) << 4;
    const int j0   = (tile & 3) << 4;
    const int tid  = threadIdx.x;
    const int ti   = tid >> 4, tj = tid & 15;

    __shared__ float s_x[3][81][84];   // 81,648 B

    for (int e = tid; e < 3 * 81 * 84; e += 256) {
        int c   = e / 6804;
        int rem = e - c * 6804;
        int u   = rem / 84;
        int v   = rem - u * 84;
        int gr  = i0 * 4 + u - 10;
        int gc  = j0 * 4 + v - 10;
        gr = gr < 0 ? -gr : (gr > 255 ? 510 - gr : gr);
        gc = gc < 0 ? -gc : (gc > 255 ? 510 - gc : gc);
        int vp = (v & 3) * 21 + (v >> 2);
        s_x[c][u][vp] = x[((b * 3 + c) * 256 + gr) * 256 + gc];
    }
    __syncthreads();

    const int p = (i0 + ti) * 64 + (j0 + tj);
    const double inv = 1.0 / (sums[b * SP + p] + 1e-8);

    float o0 = 0.f, o1 = 0.f, o2 = 0.f;
    const int t0 = g * 111;
    const int t1 = (t0 + 111 < K2) ? t0 + 111 : K2;
    for (int t = t0; t < t1; ++t) {
        int ty = t / 21, tx = t - ty * 21;
        float* kp = &kout[(size_t)(b * K2 + t) * SP + p];
        float k  = *kp;
        float kn = (float)((double)k * inv);
        *kp = kn;
        int u  = ti * 4 + ty;
        int vp = (tx & 3) * 21 + tj + (tx >> 2);
        o0 = fmaf(s_x[0][u][vp], kn, o0);
        o1 = fmaf(s_x[1][u][vp], kn, o1);
        o2 = fmaf(s_x[2][u][vp], kn, o2);
    }
    atomicAdd(&out[(b * 3 + 0) * SP + p], o0);
    atomicAdd(&out[(b * 3 + 1) * SP + p], o1);
    atomicAdd(&out[(b * 3 + 2) * SP + p], o2);
}

// ---------------------------------------------------------------------------
extern "C" void kernel_launch(void* const* d_in, const int* in_sizes, int n_in,
                              void* d_out, int out_size, void* d_ws, size_t ws_size,
                              hipStream_t stream)
{
    (void)in_sizes; (void)n_in; (void)out_size; (void)ws_size;

    const float* x = (const float*)d_in[0];
    const float* z = (const float*)d_in[1];

    float* out  = (float*)d_out;                 // (8,3,64,64)
    float* kout = (float*)d_out + NB * 3 * SP;   // (8,441,64,64) raw -> normalized

    // ws layout (doubles)
    double* wd = (double*)d_ws;
    const int n_c0wT = 3 * 576;            // 1728
    const int n_rwT  = 8 * RES_TSTRIDE;    // 294912 each
    double* c0wT = wd;
    double* rwT1 = c0wT + n_c0wT;
    double* rwT2 = rwT1 + n_rwT;
    double* c0b  = rwT2 + n_rwT;
    double* rb1  = c0b + 64;
    double* rb2  = rb1 + 512;
    double* lwT  = rb2 + 512;              // 64*448
    double* lbp  = lwT + 64 * K2P;         // 448
    double* zp   = lbp + K2P;              // 8*3*66*66
    double* hp   = zp + NB * 3 * PS2;      // 8*64*66*66 = 17.8 MB
    double* tp   = hp + NB * NF * PS2;     // 17.8 MB
    double* sums = tp;                     // aliases tp (free after conv chain)

    // zero padded buffers (borders must be 0; interiors get overwritten)
    hipMemsetAsync(zp, 0, (size_t)NB * 3 * PS2 * sizeof(double), stream);
    hipMemsetAsync(hp, 0, (size_t)NB * NF * PS2 * sizeof(double), stream);
    hipMemsetAsync(tp, 0, (size_t)NB * NF * PS2 * sizeof(double), stream);
    hipMemsetAsync(out, 0, NB * 3 * SP * sizeof(float), stream);

    // weight prep
    prep_zpad<<<(NB * 3 * SP + 255) / 256, 256, 0, stream>>>(z, zp);
    prep_convw<<<(3 * 576 + 255) / 256, 256, 0, stream>>>(
        (const float*)d_in[2], c0wT, 3, 1, 0);
    prep_convw<<<(8 * 64 * 576 + 255) / 256, 256, 0, stream>>>(
        (const float*)d_in[4], rwT1, 64, 8, RES_WSTRIDE);
    prep_convw<<<(8 * 64 * 576 + 255) / 256, 256, 0, stream>>>(
        (const float*)d_in[6], rwT2, 64, 8, RES_WSTRIDE);
    cvt_f32_to_f64<<<1, 64,  0, stream>>>((const float*)d_in[3], c0b, 64);
    cvt_f32_to_f64<<<2, 256, 0, stream>>>((const float*)d_in[5], rb1, 512);
    cvt_f32_to_f64<<<2, 256, 0, stream>>>((const float*)d_in[7], rb2, 512);
    prep_lastw<<<(64 * K2P + 255) / 256, 256, 0, stream>>>(
        (const float*)d_in[8], (const float*)d_in[9], lwT, lbp);

    conv3x3_kernel<3, 3, false, false><<<1024, 256, 0, stream>>>(zp, c0wT, c0b, nullptr, hp);
    for (int i = 0; i < 8; ++i) {
        conv3x3_kernel<64, 4, true,  false><<<1024, 256, 0, stream>>>(
            hp, rwT1 + i * RES_TSTRIDE, rb1 + i * 64, nullptr, tp);
        conv3x3_kernel<64, 4, false, true ><<<1024, 256, 0, stream>>>(
            tp, rwT2 + i * RES_TSTRIDE, rb2 + i * 64, hp, hp);
    }
    lastconv_kernel<<<512, 256, 0, stream>>>(hp, lwT, lbp, kout, sums);
    apply_kernel<<<512, 256, 0, stream>>>(x, sums, kout, out);
}